// Round 9
// baseline (239.303 us; speedup 1.0000x reference)
//
#include <hip/hip_runtime.h>

// ---- types ----
typedef short bf16x8 __attribute__((ext_vector_type(8)));
typedef float f32x4 __attribute__((ext_vector_type(4)));
typedef unsigned u32x4 __attribute__((ext_vector_type(4)));

__device__ __forceinline__ unsigned short f2bf(float f) {
  unsigned u = __builtin_bit_cast(unsigned, f);
  u += 0x7fff + ((u >> 16) & 1);   // RNE
  return (unsigned short)(u >> 16);
}

__device__ __forceinline__ void gload_lds16(const void* g, void* l) {
  __builtin_amdgcn_global_load_lds(
      (const __attribute__((address_space(1))) void*)g,
      (__attribute__((address_space(3))) void*)l, 16, 0, 0);
}

// ---- fused prep: x f32->bf16 (blocks 0..2047), W_qkv^T (2048..5119), W_proj^T (5120..6143) ----
__global__ __launch_bounds__(256) void prep(const float* __restrict__ x,
                                            const float* __restrict__ wqkv,
                                            const float* __restrict__ wproj,
                                            unsigned short* __restrict__ xb,
                                            unsigned short* __restrict__ wqkvT,
                                            unsigned short* __restrict__ wprojT) {
  __shared__ float tile[32][33];
  const int tid = threadIdx.x;
  const int bid = blockIdx.x;
  if (bid < 2048) {
    int i = bid * 256 + tid;
    const int stride = 2048 * 256;
    for (; i < 2097152; i += stride) {
      float4 v = ((const float4*)x)[i];
      ushort4 o;
      o.x = f2bf(v.x); o.y = f2bf(v.y); o.z = f2bf(v.z); o.w = f2bf(v.w);
      ((ushort4*)xb)[i] = o;
    }
    return;
  }
  const float* in;
  unsigned short* out;
  int R, C, c0, r0;
  if (bid < 5120) {
    int b = bid - 2048;
    in = wqkv; out = wqkvT; R = 1024; C = 3072;
    c0 = (b % 96) * 32; r0 = (b / 96) * 32;
  } else {
    int b = bid - 5120;
    in = wproj; out = wprojT; R = 1024; C = 1024;
    c0 = (b % 32) * 32; r0 = (b / 32) * 32;
  }
  const int tr = tid >> 3;
  const int tc4 = tid & 7;
  float4 v = *(const float4*)&in[(size_t)(r0 + tr) * C + c0 + tc4 * 4];
  tile[tr][tc4 * 4 + 0] = v.x;
  tile[tr][tc4 * 4 + 1] = v.y;
  tile[tr][tc4 * 4 + 2] = v.z;
  tile[tr][tc4 * 4 + 3] = v.w;
  __syncthreads();
#pragma unroll
  for (int i = 0; i < 4; ++i)
    out[(size_t)(c0 + tr) * R + r0 + tc4 * 4 + i] = f2bf(tile[tc4 * 4 + i][tr]);
}

// ---- V transpose per (b,h): qkv V-cols -> vT [128 bh][64 d][1024 t] ----
__global__ __launch_bounds__(256) void transpV(const unsigned short* __restrict__ qkv,
                                               unsigned short* __restrict__ vT) {
  const int tt = blockIdx.x, bh = blockIdx.y;
  const int b = bh >> 4, h = bh & 15;
  __shared__ unsigned short tile[64 * 64];
  const int tid = threadIdx.x;
  const size_t gbase = (size_t)b * 1024 * 3072 + 2048 + (size_t)h * 64;
#pragma unroll
  for (int i = 0; i < 2; ++i) {
    int c = i * 256 + tid;
    int trow = c >> 3, dc = c & 7;
    *(uint4*)(&tile[c * 8]) =
        *(const uint4*)(qkv + gbase + (size_t)(tt * 64 + trow) * 3072 + dc * 8);
  }
  __syncthreads();
  const int d = tid & 63, th = tid >> 6;
  unsigned short buf[16];
#pragma unroll
  for (int j = 0; j < 16; ++j) buf[j] = tile[(th * 16 + j) * 64 + d];
  size_t obase = ((size_t)bh * 64 + d) * 1024 + tt * 64 + th * 16;
  *(uint4*)(&vT[obase]) = *(uint4*)(&buf[0]);
  *(uint4*)(&vT[obase + 8]) = *(uint4*)(&buf[8]);
}

// ---- pipelined bf16 MFMA GEMM: C[M][N] = A[M][K](lda) * B^T[N][K] ----
// 128x128 tile, BK=32, 3-slot LDS rotation, 1 barrier/K-tile, counted vmcnt(4).
// Ledger: RAW: ds_read(t+1) safe since vmcnt(4)@iter t-1 left only tile t+2's
// loads in flight (barrier publishes). WAR: STAGE(t+3)->slot t%3 issued after
// barrier(t-1), and slot t%3's last reads finished before lgkmcnt(0)@iter t-1.
// BK=32 row stride (64B) self-interleaves banks -> no swizzle, linear staging.
template <int OUT_BF16>
__global__ __launch_bounds__(256, 3) void gemm_p3(const unsigned short* __restrict__ A,
                                                  const unsigned short* __restrict__ B,
                                                  void* __restrict__ Cv,
                                                  int M, int N, int K, int lda) {
  __shared__ unsigned short As[3][128 * 32];
  __shared__ unsigned short Bs[3][128 * 32];
  const int tid = threadIdx.x;
  const int wv = tid >> 6, lane = tid & 63;
  const int l15 = lane & 15, lg = lane >> 4;
  const int bm = blockIdx.y, bn = blockIdx.x;
  const int wr = wv >> 1, wc = wv & 1;
  f32x4 acc[4][4] = {};
  const unsigned short* Ab = A + (size_t)bm * 128 * lda;
  const unsigned short* Bb = B + (size_t)bn * 128 * K;
  const int NT = K >> 5;

  auto STAGE = [&](int t) {
    int slot = t % 3;
#pragma unroll
    for (int i = 0; i < 2; ++i) {
      int s = i * 256 + wv * 64 + lane;
      int row = s >> 2, cc = s & 3;
      gload_lds16(Ab + (size_t)row * lda + t * 32 + cc * 8,
                  (char*)(&As[slot][0]) + (size_t)(i * 256 + wv * 64) * 16);
      gload_lds16(Bb + (size_t)row * K + t * 32 + cc * 8,
                  (char*)(&Bs[slot][0]) + (size_t)(i * 256 + wv * 64) * 16);
    }
  };

  bf16x8 af[4], bf[4];

  // prologue: stage tiles 0,1,2 (12 loads/thread); tiles 0,1 landed after vmcnt(4)
  STAGE(0); STAGE(1); STAGE(2);
  asm volatile("s_waitcnt vmcnt(4)" ::: "memory");
  __builtin_amdgcn_s_barrier();
#pragma unroll
  for (int m = 0; m < 4; ++m)
    af[m] = *(const bf16x8*)(&As[0][0] + (wr * 64 + m * 16 + l15) * 32 + lg * 8);
#pragma unroll
  for (int n = 0; n < 4; ++n)
    bf[n] = *(const bf16x8*)(&Bs[0][0] + (wc * 64 + n * 16 + l15) * 32 + lg * 8);
  asm volatile("s_waitcnt lgkmcnt(0)" ::: "memory");
  __builtin_amdgcn_sched_barrier(0);
  __builtin_amdgcn_s_barrier();
  __builtin_amdgcn_sched_barrier(0);

  for (int t = 0; t < NT; ++t) {
    __builtin_amdgcn_s_setprio(1);
#pragma unroll
    for (int m = 0; m < 4; ++m)
#pragma unroll
      for (int n = 0; n < 4; ++n)
        acc[m][n] = __builtin_amdgcn_mfma_f32_16x16x32_bf16(af[m], bf[n], acc[m][n], 0, 0, 0);
    __builtin_amdgcn_s_setprio(0);
    if (t == NT - 1) break;

    const unsigned short* as = &As[(t + 1) % 3][0];
    const unsigned short* bs = &Bs[(t + 1) % 3][0];
#pragma unroll
    for (int m = 0; m < 4; ++m)
      af[m] = *(const bf16x8*)(as + (wr * 64 + m * 16 + l15) * 32 + lg * 8);
#pragma unroll
    for (int n = 0; n < 4; ++n)
      bf[n] = *(const bf16x8*)(bs + (wc * 64 + n * 16 + l15) * 32 + lg * 8);

    STAGE(t + 3 < NT ? t + 3 : NT - 1);   // clamp: idempotent restage (same bytes)

    asm volatile("s_waitcnt vmcnt(4)" ::: "memory");
    asm volatile("s_waitcnt lgkmcnt(0)" ::: "memory");
    __builtin_amdgcn_sched_barrier(0);
    __builtin_amdgcn_s_barrier();
    __builtin_amdgcn_sched_barrier(0);
  }

  asm volatile("s_waitcnt vmcnt(0)" ::: "memory");

  const int rbase = bm * 128 + wr * 64;
  const int cbase = bn * 128 + wc * 64;
#pragma unroll
  for (int m = 0; m < 4; ++m)
#pragma unroll
    for (int n = 0; n < 4; ++n)
#pragma unroll
      for (int r = 0; r < 4; ++r) {
        int row = rbase + m * 16 + lg * 4 + r;
        int col = cbase + n * 16 + l15;
        float v = acc[m][n][r];
        if (OUT_BF16)
          ((unsigned short*)Cv)[(size_t)row * N + col] = f2bf(v);
        else
          ((float*)Cv)[(size_t)row * N + col] = v;
      }
}

// ---- flash attention: swapped QK^T, in-register P exchange, no-max softmax ----
__global__ __launch_bounds__(256) void attn_fwd(const unsigned short* __restrict__ qkv,
                                                const unsigned short* __restrict__ vT,
                                                unsigned short* __restrict__ qkv_y) {
  const int bh = blockIdx.x;
  const int pair = blockIdx.y;
  const int b = bh >> 4, h = bh & 15;
  const int tid = threadIdx.x;
  const int wv = tid >> 6, lane = tid & 63;
  const int l15 = lane & 15, lg = lane >> 4;

  __shared__ unsigned short Ks[2][64 * 64];
  __shared__ unsigned short Vs[2][64 * 64];

  const size_t base = (size_t)b * 1024 * 3072;
  const float CSCL = 0.18033688f;   // 0.125 * log2(e)
  const int kq = wv * 16 + l15;

  const int idx0 = (l15 + ((lg & 1) << 5)) << 2;
  const int idx1 = idx0 + 64;
  const bool hi_nt = (lg & 2) != 0;

#pragma unroll
  for (int phase = 0; phase < 2; ++phase) {
    const int qt = phase ? 15 - pair : pair;
    const int q0 = qt * 64;
    const int qrow = q0 + wv * 16 + l15;
    const int rowg_base = q0 + wv * 16 + lg * 4;

    bf16x8 qa[2];
#pragma unroll
    for (int kh = 0; kh < 2; ++kh)
      qa[kh] = *(const bf16x8*)(qkv + base + (size_t)qrow * 3072 + h * 64 + kh * 32 + lg * 8);

    float l_sum = 0.f;
    f32x4 oacc[4] = {};

#pragma unroll
    for (int i = 0; i < 2; ++i) {
      int s = i * 256 + wv * 64 + lane;
      int row = s >> 3, pc = s & 7;
      int lc = pc ^ (row & 7);
      gload_lds16(qkv + base + (size_t)row * 3072 + 1024 + h * 64 + lc * 8,
                  (char*)(&Ks[0][0]) + (size_t)s * 16);
      gload_lds16(vT + ((size_t)bh * 64 + row) * 1024 + lc * 8,
                  (char*)(&Vs[0][0]) + (size_t)s * 16);
    }
    __syncthreads();

    for (int t = 0; t <= qt; ++t) {
      const int cur = t & 1;
      if (t < qt) {
        const int kv1 = (t + 1) * 64;
#pragma unroll
        for (int i = 0; i < 2; ++i) {
          int s = i * 256 + wv * 64 + lane;
          int row = s >> 3, pc = s & 7;
          int lc = pc ^ (row & 7);
          gload_lds16(qkv + base + (size_t)(kv1 + row) * 3072 + 1024 + h * 64 + lc * 8,
                      (char*)(&Ks[cur ^ 1][0]) + (size_t)s * 16);
          gload_lds16(vT + ((size_t)bh * 64 + row) * 1024 + kv1 + lc * 8,
                      (char*)(&Vs[cur ^ 1][0]) + (size_t)s * 16);
        }
      }

      f32x4 sacc[4] = {};
#pragma unroll
      for (int kh = 0; kh < 2; ++kh) {
        bf16x8 kf[4];
#pragma unroll
        for (int nt = 0; nt < 4; ++nt) {
          int row = nt * 16 + l15;
          int pc = (kh * 4 + lg) ^ (row & 7);
          kf[nt] = *(const bf16x8*)((const char*)(&Ks[cur][0]) + (row * 8 + pc) * 16);
        }
#pragma unroll
        for (int nt = 0; nt < 4; ++nt)
          sacc[nt] = __builtin_amdgcn_mfma_f32_16x16x32_bf16(kf[nt], qa[kh], sacc[nt], 0, 0, 0);
      }

      const bool diag = (t == qt);
      float sv[4][4];
#pragma unroll
      for (int nt = 0; nt < 4; ++nt)
#pragma unroll
        for (int r = 0; r < 4; ++r) {
          float s = sacc[nt][r] * CSCL;
          if (diag && (nt * 16 + lg * 4 + r > kq)) s = -1e30f;
          sv[nt][r] = exp2f(s);
        }

      {
        float ts = 0.f;
#pragma unroll
        for (int nt = 0; nt < 4; ++nt)
#pragma unroll
          for (int r = 0; r < 4; ++r) ts += sv[nt][r];
        ts += __shfl_xor(ts, 16);
        ts += __shfl_xor(ts, 32);
        l_sum += ts;
      }

      unsigned P2[4][2];
#pragma unroll
      for (int nt = 0; nt < 4; ++nt)
#pragma unroll
        for (int i = 0; i < 2; ++i)
          asm("v_cvt_pk_bf16_f32 %0, %1, %2"
              : "=v"(P2[nt][i]) : "v"(sv[nt][2 * i]), "v"(sv[nt][2 * i + 1]));

      u32x4 paw0, paw1;
#pragma unroll
      for (int w = 0; w < 4; ++w) {
        int idx = (w & 2) ? idx1 : idx0;
        int ri = w & 1;
        unsigned a0 = (unsigned)__builtin_amdgcn_ds_bpermute(idx, (int)P2[0][ri]);
        unsigned b0 = (unsigned)__builtin_amdgcn_ds_bpermute(idx, (int)P2[1][ri]);
        paw0[w] = hi_nt ? b0 : a0;
        unsigned a1 = (unsigned)__builtin_amdgcn_ds_bpermute(idx, (int)P2[2][ri]);
        unsigned b1 = (unsigned)__builtin_amdgcn_ds_bpermute(idx, (int)P2[3][ri]);
        paw1[w] = hi_nt ? b1 : a1;
      }
      bf16x8 pa[2];
      pa[0] = __builtin_bit_cast(bf16x8, paw0);
      pa[1] = __builtin_bit_cast(bf16x8, paw1);

#pragma unroll
      for (int kh = 0; kh < 2; ++kh)
#pragma unroll
        for (int nt = 0; nt < 4; ++nt) {
          int row = nt * 16 + l15;
          int pc = (kh * 4 + lg) ^ (row & 7);
          bf16x8 vf = *(const bf16x8*)((const char*)(&Vs[cur][0]) + (row * 8 + pc) * 16);
          oacc[nt] = __builtin_amdgcn_mfma_f32_16x16x32_bf16(pa[kh], vf, oacc[nt], 0, 0, 0);
        }
      __syncthreads();
    }

    float linv[4];
#pragma unroll
    for (int r = 0; r < 4; ++r) {
      int q = lg * 4 + r;
      float lv = __builtin_bit_cast(
          float, __builtin_amdgcn_ds_bpermute(q << 2, __builtin_bit_cast(int, l_sum)));
      linv[r] = 1.0f / lv;
    }

#pragma unroll
    for (int nt = 0; nt < 4; ++nt) {
#pragma unroll
      for (int r = 0; r < 4; ++r) {
        int row = rowg_base + r;
        int col = h * 64 + nt * 16 + l15;
        qkv_y[((size_t)b * 1024 + row) * 3072 + 2048 + col] = f2bf(oacc[nt][r] * linv[r]);
      }
    }
    __syncthreads();
  }
}

extern "C" void kernel_launch(void* const* d_in, const int* in_sizes, int n_in,
                              void* d_out, int out_size, void* d_ws, size_t ws_size,
                              hipStream_t stream) {
  const float* x = (const float*)d_in[0];
  const float* w_qkv = (const float*)d_in[1];
  const float* w_proj = (const float*)d_in[2];

  unsigned short* xb     = (unsigned short*)d_ws;
  unsigned short* vT     = (unsigned short*)d_ws;
  unsigned short* wqkvT  = (unsigned short*)((char*)d_ws + (16u << 20));
  unsigned short* wprojT = (unsigned short*)((char*)d_ws + (22u << 20));
  unsigned short* qkvb   = (unsigned short*)((char*)d_ws + (24u << 20));

  prep<<<6144, 256, 0, stream>>>(x, w_qkv, w_proj, xb, wqkvT, wprojT);

  gemm_p3<1><<<dim3(24, 64), 256, 0, stream>>>(xb, wqkvT, qkvb, 8192, 3072, 1024, 1024);

  transpV<<<dim3(16, 128), 256, 0, stream>>>(qkvb, vT);

  attn_fwd<<<dim3(128, 8), 256, 0, stream>>>(qkvb, vT, qkvb);

  gemm_p3<0><<<dim3(8, 64), 256, 0, stream>>>(qkvb + 2048, wprojT, d_out, 8192, 1024, 1024, 3072);
}

// Round 10
// 227.995 us; speedup vs baseline: 1.0496x; 1.0496x over previous
//
#include <hip/hip_runtime.h>

// ---- types ----
typedef short bf16x8 __attribute__((ext_vector_type(8)));
typedef float f32x4 __attribute__((ext_vector_type(4)));
typedef unsigned u32x4 __attribute__((ext_vector_type(4)));

__device__ __forceinline__ unsigned short f2bf(float f) {
  unsigned u = __builtin_bit_cast(unsigned, f);
  u += 0x7fff + ((u >> 16) & 1);   // RNE
  return (unsigned short)(u >> 16);
}

__device__ __forceinline__ void gload_lds16(const void* g, void* l) {
  __builtin_amdgcn_global_load_lds(
      (const __attribute__((address_space(1))) void*)g,
      (__attribute__((address_space(3))) void*)l, 16, 0, 0);
}

// ---- fused prep: x f32->bf16 (blocks 0..2047), W_qkv^T (2048..5119), W_proj^T (5120..6143) ----
__global__ __launch_bounds__(256) void prep(const float* __restrict__ x,
                                            const float* __restrict__ wqkv,
                                            const float* __restrict__ wproj,
                                            unsigned short* __restrict__ xb,
                                            unsigned short* __restrict__ wqkvT,
                                            unsigned short* __restrict__ wprojT) {
  __shared__ float tile[32][33];
  const int tid = threadIdx.x;
  const int bid = blockIdx.x;
  if (bid < 2048) {
    int i = bid * 256 + tid;
    const int stride = 2048 * 256;
    for (; i < 2097152; i += stride) {
      float4 v = ((const float4*)x)[i];
      ushort4 o;
      o.x = f2bf(v.x); o.y = f2bf(v.y); o.z = f2bf(v.z); o.w = f2bf(v.w);
      ((ushort4*)xb)[i] = o;
    }
    return;
  }
  const float* in;
  unsigned short* out;
  int R, C, c0, r0;
  if (bid < 5120) {
    int b = bid - 2048;
    in = wqkv; out = wqkvT; R = 1024; C = 3072;
    c0 = (b % 96) * 32; r0 = (b / 96) * 32;
  } else {
    int b = bid - 5120;
    in = wproj; out = wprojT; R = 1024; C = 1024;
    c0 = (b % 32) * 32; r0 = (b / 32) * 32;
  }
  const int tr = tid >> 3;
  const int tc4 = tid & 7;
  float4 v = *(const float4*)&in[(size_t)(r0 + tr) * C + c0 + tc4 * 4];
  tile[tr][tc4 * 4 + 0] = v.x;
  tile[tr][tc4 * 4 + 1] = v.y;
  tile[tr][tc4 * 4 + 2] = v.z;
  tile[tr][tc4 * 4 + 3] = v.w;
  __syncthreads();
#pragma unroll
  for (int i = 0; i < 4; ++i)
    out[(size_t)(c0 + tr) * R + r0 + tc4 * 4 + i] = f2bf(tile[tc4 * 4 + i][tr]);
}

// ---- bf16 MFMA GEMM (proven r6 structure): C[M][N] = A[M][K](lda) * B^T[N][K] ----
template <int OUT_BF16>
__global__ __launch_bounds__(256) void gemm_bt(const unsigned short* __restrict__ A,
                                               const unsigned short* __restrict__ B,
                                               void* __restrict__ Cv,
                                               int M, int N, int K, int lda) {
  __shared__ unsigned short As[128 * 64];
  __shared__ unsigned short Bs[128 * 64];
  const int tid = threadIdx.x;
  const int wv = tid >> 6, lane = tid & 63;
  const int l15 = lane & 15, lg = lane >> 4;
  const int bm = blockIdx.y, bn = blockIdx.x;
  const int wr = wv >> 1, wc = wv & 1;
  f32x4 acc[4][4] = {};
  const unsigned short* Ab = A + (size_t)bm * 128 * lda;
  const unsigned short* Bb = B + (size_t)bn * 128 * K;

  for (int k0 = 0; k0 < K; k0 += 64) {
#pragma unroll
    for (int i = 0; i < 4; ++i) {
      int s = i * 256 + wv * 64 + lane;
      int row = s >> 3, pc = s & 7;
      int lc = pc ^ (row & 7);
      gload_lds16(Ab + (size_t)row * lda + k0 + lc * 8,
                  (char*)As + (size_t)(i * 256 + wv * 64) * 16);
      gload_lds16(Bb + (size_t)row * K + k0 + lc * 8,
                  (char*)Bs + (size_t)(i * 256 + wv * 64) * 16);
    }
    __syncthreads();
#pragma unroll
    for (int kh = 0; kh < 2; ++kh) {
      bf16x8 af[4], bf[4];
#pragma unroll
      for (int m = 0; m < 4; ++m) {
        int row = wr * 64 + m * 16 + l15;
        int pc = (kh * 4 + lg) ^ (row & 7);
        af[m] = *(const bf16x8*)((const char*)As + (row * 8 + pc) * 16);
      }
#pragma unroll
      for (int n = 0; n < 4; ++n) {
        int row = wc * 64 + n * 16 + l15;
        int pc = (kh * 4 + lg) ^ (row & 7);
        bf[n] = *(const bf16x8*)((const char*)Bs + (row * 8 + pc) * 16);
      }
#pragma unroll
      for (int m = 0; m < 4; ++m)
#pragma unroll
        for (int n = 0; n < 4; ++n)
          acc[m][n] = __builtin_amdgcn_mfma_f32_16x16x32_bf16(af[m], bf[n], acc[m][n], 0, 0, 0);
    }
    __syncthreads();
  }

  const int rbase = bm * 128 + wr * 64;
  const int cbase = bn * 128 + wc * 64;
#pragma unroll
  for (int m = 0; m < 4; ++m)
#pragma unroll
    for (int n = 0; n < 4; ++n)
#pragma unroll
      for (int r = 0; r < 4; ++r) {
        int row = rbase + m * 16 + lg * 4 + r;
        int col = cbase + n * 16 + l15;
        float v = acc[m][n][r];
        if (OUT_BF16)
          ((unsigned short*)Cv)[(size_t)row * N + col] = f2bf(v);
        else
          ((float*)Cv)[(size_t)row * N + col] = v;
      }
}

// ---- flash attention: swapped QK^T, in-register P exchange, no-max softmax ----
// Inputs: qk2 [8192][2048] (Q cols 0..1023, K cols 1024..2047),
//         vT  [1024 hd][8192 bt]  (hd = h*64+d, bt = b*1024+t)  -- from gemmV
// Output: yb [8192][1024] bf16.
__global__ __launch_bounds__(256) void attn_fwd(const unsigned short* __restrict__ qk2,
                                                const unsigned short* __restrict__ vT,
                                                unsigned short* __restrict__ yb) {
  const int bh = blockIdx.x;
  const int pair = blockIdx.y;
  const int b = bh >> 4, h = bh & 15;
  const int tid = threadIdx.x;
  const int wv = tid >> 6, lane = tid & 63;
  const int l15 = lane & 15, lg = lane >> 4;

  __shared__ unsigned short Ks[2][64 * 64];
  __shared__ unsigned short Vs[2][64 * 64];

  const size_t base = (size_t)b * 1024 * 2048;
  const size_t vbase = (size_t)(h * 64) * 8192 + (size_t)b * 1024;
  const float CSCL = 0.18033688f;   // 0.125 * log2(e)
  const int kq = wv * 16 + l15;

  const int idx0 = (l15 + ((lg & 1) << 5)) << 2;
  const int idx1 = idx0 + 64;
  const bool hi_nt = (lg & 2) != 0;

#pragma unroll
  for (int phase = 0; phase < 2; ++phase) {
    const int qt = phase ? 15 - pair : pair;
    const int q0 = qt * 64;
    const int qrow = q0 + wv * 16 + l15;
    const int rowg_base = q0 + wv * 16 + lg * 4;

    bf16x8 qa[2];
#pragma unroll
    for (int kh = 0; kh < 2; ++kh)
      qa[kh] = *(const bf16x8*)(qk2 + base + (size_t)qrow * 2048 + h * 64 + kh * 32 + lg * 8);

    float l_sum = 0.f;
    f32x4 oacc[4] = {};

#pragma unroll
    for (int i = 0; i < 2; ++i) {
      int s = i * 256 + wv * 64 + lane;
      int row = s >> 3, pc = s & 7;
      int lc = pc ^ (row & 7);
      gload_lds16(qk2 + base + (size_t)row * 2048 + 1024 + h * 64 + lc * 8,
                  (char*)(&Ks[0][0]) + (size_t)s * 16);
      gload_lds16(vT + vbase + (size_t)row * 8192 + lc * 8,
                  (char*)(&Vs[0][0]) + (size_t)s * 16);
    }
    __syncthreads();

    for (int t = 0; t <= qt; ++t) {
      const int cur = t & 1;
      if (t < qt) {
        const int kv1 = (t + 1) * 64;
#pragma unroll
        for (int i = 0; i < 2; ++i) {
          int s = i * 256 + wv * 64 + lane;
          int row = s >> 3, pc = s & 7;
          int lc = pc ^ (row & 7);
          gload_lds16(qk2 + base + (size_t)(kv1 + row) * 2048 + 1024 + h * 64 + lc * 8,
                      (char*)(&Ks[cur ^ 1][0]) + (size_t)s * 16);
          gload_lds16(vT + vbase + (size_t)row * 8192 + kv1 + lc * 8,
                      (char*)(&Vs[cur ^ 1][0]) + (size_t)s * 16);
        }
      }

      f32x4 sacc[4] = {};
#pragma unroll
      for (int kh = 0; kh < 2; ++kh) {
        bf16x8 kf[4];
#pragma unroll
        for (int nt = 0; nt < 4; ++nt) {
          int row = nt * 16 + l15;
          int pc = (kh * 4 + lg) ^ (row & 7);
          kf[nt] = *(const bf16x8*)((const char*)(&Ks[cur][0]) + (row * 8 + pc) * 16);
        }
#pragma unroll
        for (int nt = 0; nt < 4; ++nt)
          sacc[nt] = __builtin_amdgcn_mfma_f32_16x16x32_bf16(kf[nt], qa[kh], sacc[nt], 0, 0, 0);
      }

      const bool diag = (t == qt);
      float sv[4][4];
#pragma unroll
      for (int nt = 0; nt < 4; ++nt)
#pragma unroll
        for (int r = 0; r < 4; ++r) {
          float s = sacc[nt][r] * CSCL;
          if (diag && (nt * 16 + lg * 4 + r > kq)) s = -1e30f;
          sv[nt][r] = exp2f(s);
        }

      {
        float ts = 0.f;
#pragma unroll
        for (int nt = 0; nt < 4; ++nt)
#pragma unroll
          for (int r = 0; r < 4; ++r) ts += sv[nt][r];
        ts += __shfl_xor(ts, 16);
        ts += __shfl_xor(ts, 32);
        l_sum += ts;
      }

      unsigned P2[4][2];
#pragma unroll
      for (int nt = 0; nt < 4; ++nt)
#pragma unroll
        for (int i = 0; i < 2; ++i)
          asm("v_cvt_pk_bf16_f32 %0, %1, %2"
              : "=v"(P2[nt][i]) : "v"(sv[nt][2 * i]), "v"(sv[nt][2 * i + 1]));

      u32x4 paw0, paw1;
#pragma unroll
      for (int w = 0; w < 4; ++w) {
        int idx = (w & 2) ? idx1 : idx0;
        int ri = w & 1;
        unsigned a0 = (unsigned)__builtin_amdgcn_ds_bpermute(idx, (int)P2[0][ri]);
        unsigned b0 = (unsigned)__builtin_amdgcn_ds_bpermute(idx, (int)P2[1][ri]);
        paw0[w] = hi_nt ? b0 : a0;
        unsigned a1 = (unsigned)__builtin_amdgcn_ds_bpermute(idx, (int)P2[2][ri]);
        unsigned b1 = (unsigned)__builtin_amdgcn_ds_bpermute(idx, (int)P2[3][ri]);
        paw1[w] = hi_nt ? b1 : a1;
      }
      bf16x8 pa[2];
      pa[0] = __builtin_bit_cast(bf16x8, paw0);
      pa[1] = __builtin_bit_cast(bf16x8, paw1);

#pragma unroll
      for (int kh = 0; kh < 2; ++kh)
#pragma unroll
        for (int nt = 0; nt < 4; ++nt) {
          int row = nt * 16 + l15;
          int pc = (kh * 4 + lg) ^ (row & 7);
          bf16x8 vf = *(const bf16x8*)((const char*)(&Vs[cur][0]) + (row * 8 + pc) * 16);
          oacc[nt] = __builtin_amdgcn_mfma_f32_16x16x32_bf16(pa[kh], vf, oacc[nt], 0, 0, 0);
        }
      __syncthreads();
    }

    float linv[4];
#pragma unroll
    for (int r = 0; r < 4; ++r) {
      int q = lg * 4 + r;
      float lv = __builtin_bit_cast(
          float, __builtin_amdgcn_ds_bpermute(q << 2, __builtin_bit_cast(int, l_sum)));
      linv[r] = 1.0f / lv;
    }

#pragma unroll
    for (int nt = 0; nt < 4; ++nt) {
#pragma unroll
      for (int r = 0; r < 4; ++r) {
        int row = rowg_base + r;
        int col = h * 64 + nt * 16 + l15;
        yb[((size_t)b * 1024 + row) * 1024 + col] = f2bf(oacc[nt][r] * linv[r]);
      }
    }
    __syncthreads();
  }
}

extern "C" void kernel_launch(void* const* d_in, const int* in_sizes, int n_in,
                              void* d_out, int out_size, void* d_ws, size_t ws_size,
                              hipStream_t stream) {
  const float* x = (const float*)d_in[0];
  const float* w_qkv = (const float*)d_in[1];
  const float* w_proj = (const float*)d_in[2];

  // workspace (72MB):
  //   [0,16MB)   x_bf16 [8192][1024]; dead after gemmV -> reused as y bf16
  //   [16,22MB)  w_qkv^T bf16 [3072][1024]
  //   [22,24MB)  w_proj^T bf16 [1024][1024]
  //   [24,56MB)  qk2 bf16 [8192][2048]  (Q | K)
  //   [56,72MB)  vT bf16 [1024 hd][8192 bt]  (direct from gemmV)
  unsigned short* xb     = (unsigned short*)d_ws;
  unsigned short* yb     = (unsigned short*)d_ws;
  unsigned short* wqkvT  = (unsigned short*)((char*)d_ws + (16u << 20));
  unsigned short* wprojT = (unsigned short*)((char*)d_ws + (22u << 20));
  unsigned short* qk2    = (unsigned short*)((char*)d_ws + (24u << 20));
  unsigned short* vT     = (unsigned short*)((char*)d_ws + (56u << 20));

  prep<<<6144, 256, 0, stream>>>(x, w_qkv, w_proj, xb, wqkvT, wprojT);

  // Q,K: [8192][2048] = xb @ (W_qkv cols 0..2047)^T
  gemm_bt<1><<<dim3(16, 64), 256, 0, stream>>>(xb, wqkvT, qk2, 8192, 2048, 1024, 1024);

  // V^T direct: [1024 hd][8192 bt] = (W_qkv cols 2048..3071)^T @ x^T
  gemm_bt<1><<<dim3(64, 8), 256, 0, stream>>>(wqkvT + 2048 * 1024, xb, vT, 1024, 8192, 1024, 1024);

  attn_fwd<<<dim3(128, 8), 256, 0, stream>>>(qk2, vT, yb);

  gemm_bt<0><<<dim3(8, 64), 256, 0, stream>>>(yb, wprojT, d_out, 8192, 1024, 1024, 1024);
}